// Round 1
// baseline (69.014 us; speedup 1.0000x reference)
//
#include <hip/hip_runtime.h>
#include <math.h>

// Problem constants
#define BATCH 32
#define SEQ   512
#define DIN   512
#define IFACE 919
#define NW    1024   // WORDS_NUM
#define WS    128    // WORD_SIZE
#define RH    4      // READ_HEADS

// iface tail: we only need columns 645..918 (274 columns)
// c = j - 645: erase = c[0:128], write_vec = c[128:256], free_gates = c[256:260],
// alloc_gate = c[260], write_gate = c[261], read_modes[m][r] = c[262 + m*4 + r]
#define TAILC 274
#define TAIL0 645

// ws float offsets
#define XM_PART 0            // 32 * 16 * 512 = 262144 (partial seq sums)
#define IFC     262144       // 32 * 274 = 8768
#define EVO     270912       // 32 * 128 (sigmoid erase)
#define WVO     275008       // 32 * 128 (write vector)
#define WWH     279104       // 32 * 64  (ww for n<64)
#define SCAL    281152       // 32 * 8   ([0]=u, [1]=wwc)
#define RWV     281408       // 32 * 4   (rw per head)

// d_out float offsets (tuple concat: out, memory, link, usage, prec, ww, rw)
#define OUT_OFF   0            // 32*512       = 16384
#define MEM_OFF   16384        // 32*1024*128  = 4194304
#define LINK_OFF  4210688      // 32*1024*1024 = 33554432 (all zeros)
#define USAGE_OFF 37765120     // 32*1024
#define PREC_OFF  37797888     // 32*1024
#define WW_OFF    37830656     // 32*1024
#define RW_OFF    37863424     // 32*1024*4    = 131072
// total = 37994496 floats

__device__ __forceinline__ float sigmoidf_(float x) { return 1.0f / (1.0f + expf(-x)); }

// K0: zero the link output (exactly 0) — 134 MB, float4 stores
__global__ void k_zero_link(float4* __restrict__ dst, int count4) {
    int idx = blockIdx.x * blockDim.x + threadIdx.x;
    int stride = gridDim.x * blockDim.x;
    float4 z = {0.f, 0.f, 0.f, 0.f};
    for (int i = idx; i < count4; i += stride) dst[i] = z;
}

// K1: partial reduce of x over seq. grid (16 chunks, 32 batch), 128 threads (float4 per lane)
__global__ void k_reduce_x(const float* __restrict__ x, float* __restrict__ ws) {
    int c = blockIdx.x, b = blockIdx.y, t = threadIdx.x;
    const float4* xr = (const float4*)(x + (size_t)(b * SEQ + c * 32) * DIN);
    float4 acc = {0.f, 0.f, 0.f, 0.f};
    for (int s = 0; s < 32; ++s) {
        float4 v = xr[s * 128 + t];
        acc.x += v.x; acc.y += v.y; acc.z += v.z; acc.w += v.w;
    }
    ((float4*)(ws + XM_PART))[(b * 16 + c) * 128 + t] = acc;
}

// K2: iface tail = (mean_x) @ W[:, 645:919]. grid (2, 32), 256 threads
__global__ void k_iface(float* __restrict__ ws, const float* __restrict__ Wif) {
    __shared__ float xms[DIN];
    int b = blockIdx.y, t = threadIdx.x;
    for (int d = t; d < DIN; d += 256) {
        const float* p = ws + XM_PART + (size_t)b * 16 * DIN + d;
        float s = 0.f;
        #pragma unroll
        for (int c = 0; c < 16; ++c) s += p[c * DIN];
        xms[d] = s;
    }
    __syncthreads();
    int j = blockIdx.x * 256 + t;
    if (j >= TAILC) return;
    float acc = 0.f;
    for (int k = 0; k < DIN; ++k) acc += xms[k] * Wif[k * IFACE + TAIL0 + j];
    ws[IFC + b * TAILC + j] = acc * (1.0f / SEQ);
}

// K3: per-batch parameters + "out" output. grid 32, 128 threads
__global__ void k_params(float* __restrict__ ws, float* __restrict__ out) {
    int b = blockIdx.x, t = threadIdx.x;  // t < 128
    const float* p = ws + IFC + b * TAILC;

    // erase (sigmoid) and write vector
    ws[EVO + b * 128 + t] = sigmoidf_(p[t]);
    ws[WVO + b * 128 + t] = p[128 + t];

    // read_modes softmax over m (redundant per thread, cheap)
    float rm1[RH];
    #pragma unroll
    for (int r = 0; r < RH; ++r) {
        float i0 = p[262 + r], i1 = p[266 + r], i2 = p[270 + r];
        float mx = fmaxf(i0, fmaxf(i1, i2));
        float e0 = expf(i0 - mx), e1 = expf(i1 - mx), e2 = expf(i2 - mx);
        rm1[r] = e1 / (e0 + e1 + e2);
    }

    // out[b, w*4 + r] = 1e-6 * rm1[r]  (read_vectors collapse)
    float4 o = {1e-6f * rm1[0], 1e-6f * rm1[1], 1e-6f * rm1[2], 1e-6f * rm1[3]};
    ((float4*)(out + OUT_OFF))[b * 128 + t] = o;

    if (t == 0) {
        const float inv1024 = 1.0f / 1024.0f;
        float ret = 1.f;
        #pragma unroll
        for (int r = 0; r < RH; ++r) {
            float rwv = rm1[r] * inv1024;
            ws[RWV + b * 4 + r] = rwv;
            float fg = sigmoidf_(p[256 + r]);
            ret *= (1.f - fg * rwv);
        }
        float u = 1e-6f * ret;                 // usage value (constant over n)
        float ag = sigmoidf_(p[260]);
        float wg = sigmoidf_(p[261]);
        float wwc = wg * (ag * 0.0f + (1.f - ag) * inv1024);  // ww for n >= 64
        ws[SCAL + b * 8 + 0] = u;
        ws[SCAL + b * 8 + 1] = wwc;
        // alloc[n] = (1-u) * u^n  (same sequential f32 cumprod as reference)
        float cum = 1.f;
        for (int n = 0; n < 64; ++n) {
            float alloc = (1.f - u) * cum;
            ws[WWH + b * 64 + n] = wg * (ag * alloc + (1.f - ag) * inv1024);
            cum *= u;
        }
    }
}

// K5: memory fill, 4096 blocks x 256 threads, float4 per thread (16.8 MB write)
__global__ void k_memory(const float* __restrict__ ws, float* __restrict__ out) {
    int idx = blockIdx.x * 256 + threadIdx.x;   // < 1048576 float4
    int w4 = idx & 31;
    int n  = (idx >> 5) & 1023;
    int b  = idx >> 15;
    float ww = (n < 64) ? ws[WWH + b * 64 + n] : ws[SCAL + b * 8 + 1];
    float4 e = ((const float4*)(ws + EVO))[b * 32 + w4];
    float4 v = ((const float4*)(ws + WVO))[b * 32 + w4];
    float4 m;
    m.x = 1e-6f * (1.f - ww * e.x) + ww * v.x;
    m.y = 1e-6f * (1.f - ww * e.y) + ww * v.y;
    m.z = 1e-6f * (1.f - ww * e.z) + ww * v.z;
    m.w = 1e-6f * (1.f - ww * e.w) + ww * v.w;
    ((float4*)(out + MEM_OFF))[idx] = m;
}

// K6: usage / prec / ww / rw outputs. 128 blocks x 256 threads
__global__ void k_small(const float* __restrict__ ws, float* __restrict__ out) {
    int t = blockIdx.x * 256 + threadIdx.x;     // < 32768
    int b = t >> 10, n = t & 1023;
    float u  = ws[SCAL + b * 8 + 0];
    float ww = (n < 64) ? ws[WWH + b * 64 + n] : ws[SCAL + b * 8 + 1];
    out[USAGE_OFF + t] = u;
    out[PREC_OFF + t]  = ww;   // prec = ww (prec0 = 0)
    out[WW_OFF + t]    = ww;
    float4 rv = ((const float4*)(ws + RWV))[b];
    ((float4*)out)[RW_OFF / 4 + t] = rv;       // rw[b,n,:] constant over n
}

extern "C" void kernel_launch(void* const* d_in, const int* in_sizes, int n_in,
                              void* d_out, int out_size, void* d_ws, size_t ws_size,
                              hipStream_t stream) {
    const float* x   = (const float*)d_in[0];
    const float* Wif = (const float*)d_in[1];
    float* out = (float*)d_out;
    float* ws  = (float*)d_ws;

    // link output is exactly zero (link0 = 0, prec0 = 0)
    k_zero_link<<<8192, 256, 0, stream>>>((float4*)(out + LINK_OFF), 33554432 / 4);
    k_reduce_x<<<dim3(16, 32), 128, 0, stream>>>(x, ws);
    k_iface<<<dim3(2, 32), 256, 0, stream>>>(ws, Wif);
    k_params<<<32, 128, 0, stream>>>(ws, out);
    k_memory<<<4096, 256, 0, stream>>>(ws, out);
    k_small<<<128, 256, 0, stream>>>(ws, out);
}